// Round 2
// baseline (6854.475 us; speedup 1.0000x reference)
//
#include <hip/hip_runtime.h>
#include <math.h>

// GatedDeltaNet forward, MI355X round 1: fp32 math, bf16 storage for big
// intermediates (cuts workspace 372 MB -> 162 MB; round-0 crash was almost
// certainly d_ws overflow). B=2 L=4096 D=2048 H=16 Dh=128 C=64 KW=4
#define B_   2
#define L_   4096
#define D_   2048
#define H_   16
#define DH   128
#define CH   64          // chunk length C
#define NCH  64          // number of chunks L/C
#define HD   2048        // H*Dh
#define BH   32          // B*H
#define BHL  131072      // B*H*L
#define PSZ  16777216ull // B*L*HD elements (one full activation tensor)

typedef unsigned short u16;

static __device__ __forceinline__ float sigm(float x) { return 1.0f / (1.0f + expf(-x)); }

static __device__ __forceinline__ float b2f(u16 u) {
    union { float f; unsigned int i; } v; v.i = ((unsigned int)u) << 16; return v.f;
}
static __device__ __forceinline__ u16 f2b(float f) {
    union { float f; unsigned int i; } v; v.f = f;
    unsigned int r = v.i + 0x7fffu + ((v.i >> 16) & 1u);
    return (u16)(r >> 16);
}
// load 8 bf16 (16B) -> 8 floats (dst must be 16B aligned)
static __device__ __forceinline__ void b8ld(const u16* p, float* d) {
    uint4 u = *(const uint4*)p;
    float4 a, b;
    a.x = b2f((u16)(u.x & 0xffff)); a.y = b2f((u16)(u.x >> 16));
    a.z = b2f((u16)(u.y & 0xffff)); a.w = b2f((u16)(u.y >> 16));
    b.x = b2f((u16)(u.z & 0xffff)); b.y = b2f((u16)(u.z >> 16));
    b.z = b2f((u16)(u.w & 0xffff)); b.w = b2f((u16)(u.w >> 16));
    *(float4*)d = a; *(float4*)(d + 4) = b;
}
// store 8 floats -> 8 bf16 (16B)
static __device__ __forceinline__ void b8st(const float* s, u16* p) {
    uint4 u;
    u.x = (unsigned)f2b(s[0]) | ((unsigned)f2b(s[1]) << 16);
    u.y = (unsigned)f2b(s[2]) | ((unsigned)f2b(s[3]) << 16);
    u.z = (unsigned)f2b(s[4]) | ((unsigned)f2b(s[5]) << 16);
    u.w = (unsigned)f2b(s[6]) | ((unsigned)f2b(s[7]) << 16);
    *(uint4*)p = u;
}
// 4-element A-tile loads for gemm (fp32 or bf16 source)
static __device__ __forceinline__ float4 ldA4(const float* p) { return *(const float4*)p; }
static __device__ __forceinline__ float4 ldA4(const u16* p) {
    ushort4 u = *(const ushort4*)p;
    float4 f; f.x = b2f(u.x); f.y = b2f(u.y); f.z = b2f(u.z); f.w = b2f(u.w); return f;
}
// 4-element C-tile stores (fp32 or bf16 dest)
static __device__ __forceinline__ void st4(float* p, const float* a) {
    float4 v; v.x = a[0]; v.y = a[1]; v.z = a[2]; v.w = a[3]; *(float4*)p = v;
}
static __device__ __forceinline__ void st4(u16* p, const float* a) {
    ushort4 v; v.x = f2b(a[0]); v.y = f2b(a[1]); v.z = f2b(a[2]); v.w = f2b(a[3]);
    *(ushort4*)p = v;
}

// ---------------------------------------------------------------------------
// Tiled fp32-math GEMM:  C[M,N] = A[M,K] @ B[N,K]^T   (both K-contiguous)
// 128x128 tile, BK=32, 256 threads, 8x8 per thread, LDS stored transposed.
// TA in {float,u16}; TC in {float,u16}. M,N mult of 128; K mult of 32.
// ---------------------------------------------------------------------------
template <typename TA, typename TC>
__global__ __launch_bounds__(256) void gemm_nt(const TA* __restrict__ A,
                                               const float* __restrict__ Bm,
                                               TC* __restrict__ Cm,
                                               int M, int N, int K) {
    __shared__ __align__(16) float sA[32 * 132];
    __shared__ __align__(16) float sB[32 * 132];
    const int tid = threadIdx.x;
    const int bx = blockIdx.x;  // N tile
    const int by = blockIdx.y;  // M tile
    const int tx = tid & 15, ty = tid >> 4;
    const int mbase = by * 128, nbase = bx * 128;

    float acc[8][8];
#pragma unroll
    for (int r = 0; r < 8; r++)
#pragma unroll
        for (int c = 0; c < 8; c++) acc[r][c] = 0.0f;

    for (int k0 = 0; k0 < K; k0 += 32) {
#pragma unroll
        for (int i = 0; i < 4; i++) {
            int f = tid + 256 * i;
            int m = f >> 3, kq = f & 7;
            float4 va = ldA4(A + (size_t)(mbase + m) * K + k0 + kq * 4);
            sA[(kq * 4 + 0) * 132 + m] = va.x;
            sA[(kq * 4 + 1) * 132 + m] = va.y;
            sA[(kq * 4 + 2) * 132 + m] = va.z;
            sA[(kq * 4 + 3) * 132 + m] = va.w;
            float4 vb = *(const float4*)(Bm + (size_t)(nbase + m) * K + k0 + kq * 4);
            sB[(kq * 4 + 0) * 132 + m] = vb.x;
            sB[(kq * 4 + 1) * 132 + m] = vb.y;
            sB[(kq * 4 + 2) * 132 + m] = vb.z;
            sB[(kq * 4 + 3) * 132 + m] = vb.w;
        }
        __syncthreads();
#pragma unroll
        for (int kk = 0; kk < 32; kk++) {
            float4 a0 = *(const float4*)&sA[kk * 132 + ty * 8];
            float4 a1 = *(const float4*)&sA[kk * 132 + ty * 8 + 4];
            float4 b0 = *(const float4*)&sB[kk * 132 + tx * 8];
            float4 b1 = *(const float4*)&sB[kk * 132 + tx * 8 + 4];
            float ar[8] = {a0.x, a0.y, a0.z, a0.w, a1.x, a1.y, a1.z, a1.w};
            float br[8] = {b0.x, b0.y, b0.z, b0.w, b1.x, b1.y, b1.z, b1.w};
#pragma unroll
            for (int r = 0; r < 8; r++)
#pragma unroll
                for (int c = 0; c < 8; c++) acc[r][c] += ar[r] * br[c];
        }
        __syncthreads();
    }
#pragma unroll
    for (int r = 0; r < 8; r++) {
        TC* cp = Cm + (size_t)(mbase + ty * 8 + r) * N + nbase + tx * 8;
        st4(cp, &acc[r][0]);
        st4(cp + 4, &acc[r][4]);
    }
}

// ---------------------------------------------------------------------------
// Causal depthwise conv (KW=4) + SiLU + optional L2 norm over Dh.
// in:  pre (B, L, HD) bf16.  out: (B, H, L, Dh) bf16.
// mode 0: q (l2 norm, /sqrt(Dh)); mode 1: k (l2 norm); mode 2: v (none)
// One wave per (b,h,l); lane handles d = lane and lane+64.
// ---------------------------------------------------------------------------
__global__ __launch_bounds__(256) void conv_silu_norm(const u16* __restrict__ pre,
                                                      const float* __restrict__ w,
                                                      u16* __restrict__ out, int mode) {
    int wid = blockIdx.x * 4 + (threadIdx.x >> 6);  // global (b,h,l) id
    int lane = threadIdx.x & 63;
    int l = wid & (L_ - 1);
    int bh = wid >> 12;  // /L_
    int b = bh >> 4, h = bh & 15;

    float vals[2];
    float sumsq = 0.0f;
#pragma unroll
    for (int s = 0; s < 2; s++) {
        int d = lane + 64 * s;
        int c = h * DH + d;
        const u16* col = pre + (size_t)b * L_ * HD + c;
        float acc = 0.0f;
        if (l >= 3) {
            acc = w[c * 4 + 0] * b2f(col[(size_t)(l - 3) * HD]) +
                  w[c * 4 + 1] * b2f(col[(size_t)(l - 2) * HD]) +
                  w[c * 4 + 2] * b2f(col[(size_t)(l - 1) * HD]) +
                  w[c * 4 + 3] * b2f(col[(size_t)l * HD]);
        } else {
#pragma unroll
            for (int j = 0; j < 4; j++) {
                int ll = l - 3 + j;
                if (ll >= 0) acc += w[c * 4 + j] * b2f(col[(size_t)ll * HD]);
            }
        }
        float y = acc * sigm(acc);  // SiLU
        vals[s] = y;
        sumsq += y * y;
    }
    if (mode < 2) {
#pragma unroll
        for (int m = 32; m >= 1; m >>= 1) sumsq += __shfl_xor(sumsq, m, 64);
        float scale = 1.0f / fmaxf(sqrtf(sumsq), 1e-12f);
        if (mode == 0) scale *= 0.08838834764831843f;  // 1/sqrt(128)
        vals[0] *= scale;
        vals[1] *= scale;
    }
    u16* o = out + ((size_t)bh * L_ + l) * DH;
    o[lane] = f2b(vals[0]);
    o[lane + 64] = f2b(vals[1]);
}

// ---------------------------------------------------------------------------
// Small projections: bpre/apre (B,L,H) = x @ Wb^T / x @ Wa^T. One wave per row.
// ---------------------------------------------------------------------------
__global__ __launch_bounds__(64) void proj_small(const float* __restrict__ x,
                                                 const float* __restrict__ Wb,
                                                 const float* __restrict__ Wa,
                                                 float* __restrict__ bpre,
                                                 float* __restrict__ apre) {
    int row = blockIdx.x;
    int lane = threadIdx.x;
    const float* xr = x + (size_t)row * D_;
    float xv[32];
#pragma unroll
    for (int j = 0; j < 32; j++) xv[j] = xr[lane + 64 * j];
    for (int h = 0; h < 16; h++) {
        const float* wr = Wb + (size_t)h * D_;
        float acc = 0.0f;
#pragma unroll
        for (int j = 0; j < 32; j++) acc += xv[j] * wr[lane + 64 * j];
#pragma unroll
        for (int m = 32; m >= 1; m >>= 1) acc += __shfl_xor(acc, m, 64);
        if (lane == 0) bpre[(size_t)row * 16 + h] = acc;
    }
    for (int h = 0; h < 16; h++) {
        const float* wr = Wa + (size_t)h * D_;
        float acc = 0.0f;
#pragma unroll
        for (int j = 0; j < 32; j++) acc += xv[j] * wr[lane + 64 * j];
#pragma unroll
        for (int m = 32; m >= 1; m >>= 1) acc += __shfl_xor(acc, m, 64);
        if (lane == 0) apre[(size_t)row * 16 + h] = acc;
    }
}

// beta = sigmoid(bpre); g = -exp(A_log)*softplus(apre + dt_bias); layout (B,H,L)
__global__ __launch_bounds__(256) void beta_g_k(const float* __restrict__ bpre,
                                                const float* __restrict__ apre,
                                                const float* __restrict__ A_log,
                                                const float* __restrict__ dt_bias,
                                                float* __restrict__ beta, float* __restrict__ g) {
    int gi = blockIdx.x * 256 + threadIdx.x;  // < BHL
    int l = gi & (L_ - 1);
    int bh = gi >> 12;
    int b = bh >> 4, h = bh & 15;
    float bp = bpre[((size_t)b * L_ + l) * 16 + h];
    float ap = apre[((size_t)b * L_ + l) * 16 + h] + dt_bias[h];
    float sp = (ap > 20.0f) ? ap : log1pf(expf(ap));
    beta[(size_t)bh * L_ + l] = 1.0f / (1.0f + expf(-bp));
    g[(size_t)bh * L_ + l] = -expf(A_log[h]) * sp;
}

// ---------------------------------------------------------------------------
// Per-chunk prep (fully parallel over B*H*N = 2048 blocks):
//   decay cumsum, A = I + beta*exp(dlg)*(K K^T) (strict lower),
//   in-place inversion T = A^{-1} (unit lower), Wm = T@(beta*gamma*K),
//   U = T@(beta*V) (overwrites V), W2 = (Q K^T)*GM (incl lower),
//   q <- q*gamma (Qd), k <- k*gCr (Kd), gamC out. All storage bf16, math fp32.
// ---------------------------------------------------------------------------
__global__ __launch_bounds__(256) void prep_chunks(u16* __restrict__ q, u16* __restrict__ k,
                                                   u16* __restrict__ v,
                                                   const float* __restrict__ beta,
                                                   const float* __restrict__ g,
                                                   u16* __restrict__ Wm, float* __restrict__ W2,
                                                   float* __restrict__ gamC) {
    __shared__ __align__(16) float sK[CH * DH];  // 32 KB (fp32)
    __shared__ __align__(16) float sA[CH * CH];  // 16 KB, A then T in place
    __shared__ float sLg[CH], sGam[CH], sGcr[CH], sBeta[CH];

    const int cid = blockIdx.x;
    const int bh = cid >> 6, n = cid & 63;
    const int tid = threadIdx.x;
    const size_t cbase = ((size_t)bh * L_ + (size_t)n * CH) * DH;
    u16* qw = q + cbase;
    u16* kw = k + cbase;
    const u16* vc = v + cbase;

    // S0: decay scan (wave 0) + stage K into LDS (bf16 -> fp32)
    if (tid < 64) {
        float lg = g[(size_t)bh * L_ + (size_t)n * CH + tid];
#pragma unroll
        for (int off = 1; off < 64; off <<= 1) {
            float u = __shfl_up(lg, off, 64);
            if (tid >= off) lg += u;
        }
        float lgC = __shfl(lg, 63, 64);
        sLg[tid] = lg;
        sGam[tid] = expf(lg);
        sGcr[tid] = expf(lgC - lg);
        sBeta[tid] = beta[(size_t)bh * L_ + (size_t)n * CH + tid];
        if (tid == 63) gamC[cid] = expf(lgC);
    }
    for (int idx = tid; idx < CH * DH / 8; idx += 256)
        b8ld(kw + (size_t)idx * 8, &sK[idx * 8]);
    __syncthreads();

    // S1: build A (diag=1, upper=0) and W2 (reads global q bf16, LDS K fp32)
    {
        int bi = tid >> 4, bj = tid & 15;
        int i0 = bi * 4, j0 = bj * 4;
        float* w2c = W2 + (size_t)cid * CH * CH;
        if (bi >= bj) {
            float dotA[4][4], dotQ[4][4];
#pragma unroll
            for (int r = 0; r < 4; r++)
#pragma unroll
                for (int c = 0; c < 4; c++) { dotA[r][c] = 0.0f; dotQ[r][c] = 0.0f; }
            for (int e = 0; e < DH; e += 4) {
                float4 ka[4], kb[4], qa[4];
#pragma unroll
                for (int r = 0; r < 4; r++) {
                    ka[r] = *(const float4*)&sK[(i0 + r) * DH + e];
                    qa[r] = ldA4(qw + (size_t)(i0 + r) * DH + e);
                }
#pragma unroll
                for (int c = 0; c < 4; c++) kb[c] = *(const float4*)&sK[(j0 + c) * DH + e];
#pragma unroll
                for (int r = 0; r < 4; r++)
#pragma unroll
                    for (int c = 0; c < 4; c++) {
                        dotA[r][c] += ka[r].x * kb[c].x + ka[r].y * kb[c].y + ka[r].z * kb[c].z + ka[r].w * kb[c].w;
                        dotQ[r][c] += qa[r].x * kb[c].x + qa[r].y * kb[c].y + qa[r].z * kb[c].z + qa[r].w * kb[c].w;
                    }
            }
#pragma unroll
            for (int r = 0; r < 4; r++)
#pragma unroll
                for (int c = 0; c < 4; c++) {
                    int i = i0 + r, j = j0 + c;
                    float dexp = expf(sLg[i] - sLg[j]);
                    sA[i * CH + j] = (j < i) ? sBeta[i] * dexp * dotA[r][c] : ((j == i) ? 1.0f : 0.0f);
                    w2c[i * CH + j] = (j <= i) ? dotQ[r][c] * dexp : 0.0f;
                }
        } else {
#pragma unroll
            for (int r = 0; r < 4; r++)
#pragma unroll
                for (int c = 0; c < 4; c++) {
                    sA[(i0 + r) * CH + j0 + c] = 0.0f;
                    w2c[(i0 + r) * CH + j0 + c] = 0.0f;
                }
        }
    }
    __syncthreads();

    // S2: scale global q->Qd, k->Kd (bf16 in place); LDS K -> beta*gamma*K
    for (int idx = tid; idx < CH * DH; idx += 256) {
        int i = idx >> 7;
        qw[idx] = f2b(b2f(qw[idx]) * sGam[i]);
        kw[idx] = f2b(b2f(kw[idx]) * sGcr[i]);
        sK[idx] *= sBeta[i] * sGam[i];
    }
    __syncthreads();

    // S3: in-place unit-lower-triangular inversion: sA rows become T rows.
    for (int i = 1; i < 64; i++) {
        float xj = 0.0f;
        bool act = (tid < i);
        if (act) {
            float acc2 = 0.0f;
            for (int kk = 0; kk < i; kk++) acc2 += sA[i * CH + kk] * sA[kk * CH + tid];
            xj = -acc2;
        }
        __syncthreads();
        if (act) sA[i * CH + tid] = xj;
        __syncthreads();
    }

    // S4: Wm = T @ (beta*gamma*K); U = T @ (beta*V) (V streamed, bf16)
    {
        int ib = tid >> 4, cb = tid & 15;
        int i0 = ib * 4, c0 = cb * 8;
        float accK[4][8], accV[4][8];
#pragma unroll
        for (int r = 0; r < 4; r++)
#pragma unroll
            for (int c = 0; c < 8; c++) { accK[r][c] = 0.0f; accV[r][c] = 0.0f; }
        for (int kk = 0; kk < CH; kk += 4) {
            float tr[4][4];
#pragma unroll
            for (int r = 0; r < 4; r++) {
                float4 t4 = *(const float4*)&sA[(i0 + r) * CH + kk];
                tr[r][0] = t4.x; tr[r][1] = t4.y; tr[r][2] = t4.z; tr[r][3] = t4.w;
            }
#pragma unroll
            for (int s = 0; s < 4; s++) {
                int kks = kk + s;
                float va[8], ka[8];
                b8ld(vc + (size_t)kks * DH + c0, va);
                float bv = sBeta[kks];
#pragma unroll
                for (int c = 0; c < 8; c++) { va[c] *= bv; ka[c] = sK[kks * DH + c0 + c]; }
#pragma unroll
                for (int r = 0; r < 4; r++) {
                    float t = tr[r][s];
#pragma unroll
                    for (int c = 0; c < 8; c++) {
                        accK[r][c] += t * ka[c];
                        accV[r][c] += t * va[c];
                    }
                }
            }
        }
        u16* wmc = Wm + (size_t)cid * CH * DH;
#pragma unroll
        for (int r = 0; r < 4; r++) b8st(&accK[r][0], wmc + (size_t)(i0 + r) * DH + c0);
        __syncthreads();  // all V reads complete before overwriting with U
        u16* uc = v + cbase;
#pragma unroll
        for (int r = 0; r < 4; r++) b8st(&accV[r][0], uc + (size_t)(i0 + r) * DH + c0);
    }
}

// ---------------------------------------------------------------------------
// Sequential inter-chunk scan. Row-parallel in d: grid = B*H * 4 d-blocks of 32.
// Per chunk: mid = U - Wm@S^T; O = Qd@S^T + W2@mid; S = gamC*S + mid^T@Kd.
// S slice (32x128, fp32) lives in LDS. Streams bf16; O written fp32 to d_out.
// ---------------------------------------------------------------------------
__global__ __launch_bounds__(256) void scan_seq(const u16* __restrict__ Wm,
                                                const u16* __restrict__ U,
                                                const u16* __restrict__ Qd,
                                                const u16* __restrict__ Kd,
                                                const float* __restrict__ W2,
                                                const float* __restrict__ gamC,
                                                const float* __restrict__ S0,
                                                float* __restrict__ Og,
                                                float* __restrict__ Sfin) {
    __shared__ __align__(16) float sS[32 * DH];   // 16 KB: S rows d0..d0+31
    __shared__ __align__(16) float sWQ[CH * DH];  // 32 KB: Wm, then Qd
    __shared__ __align__(16) float sM[CH * 32];   // 8 KB: U slice -> mid

    const int bid = blockIdx.x;
    const int bh = bid >> 2, dblk = bid & 3;
    const int d0 = dblk * 32;
    const int tid = threadIdx.x;

    for (int idx = tid; idx < 32 * DH; idx += 256)
        sS[idx] = S0[(size_t)bh * DH * DH + (size_t)(d0 + (idx >> 7)) * DH + (idx & 127)];
    __syncthreads();

    for (int n = 0; n < NCH; n++) {
        const size_t cid = (size_t)bh * NCH + n;
        const u16* wmc = Wm + cid * CH * DH;
        const u16* uc = U + ((size_t)bh * L_ + (size_t)n * CH) * DH;
        const u16* qc = Qd + ((size_t)bh * L_ + (size_t)n * CH) * DH;
        const u16* kc = Kd + ((size_t)bh * L_ + (size_t)n * CH) * DH;
        const float* w2c = W2 + cid * CH * CH;
        const float gC = gamC[cid];

        // P0: stage Wm and the U d-slice
        for (int idx = tid; idx < CH * DH / 8; idx += 256)
            b8ld(wmc + (size_t)idx * 8, &sWQ[idx * 8]);
        for (int idx = tid; idx < CH * 32 / 4; idx += 256) {
            int i = idx >> 3, c4 = idx & 7;
            ushort4 u = *(const ushort4*)(uc + (size_t)i * DH + d0 + c4 * 4);
            float4 f; f.x = b2f(u.x); f.y = b2f(u.y); f.z = b2f(u.z); f.w = b2f(u.w);
            *(float4*)&sM[idx * 4] = f;
        }
        __syncthreads();

        // P1: mid = U - Wm @ S^T (4i x 2d per thread)
        {
            int ib = tid >> 4, db = tid & 15;
            int i0 = ib * 4, dd0 = db * 2;
            float acc[4][2];
#pragma unroll
            for (int r = 0; r < 4; r++) { acc[r][0] = 0.0f; acc[r][1] = 0.0f; }
            for (int e = 0; e < DH; e += 4) {
                float4 w4[4], s4[2];
#pragma unroll
                for (int r = 0; r < 4; r++) w4[r] = *(const float4*)&sWQ[(i0 + r) * DH + e];
#pragma unroll
                for (int c = 0; c < 2; c++) s4[c] = *(const float4*)&sS[(dd0 + c) * DH + e];
#pragma unroll
                for (int r = 0; r < 4; r++)
#pragma unroll
                    for (int c = 0; c < 2; c++)
                        acc[r][c] += w4[r].x * s4[c].x + w4[r].y * s4[c].y + w4[r].z * s4[c].z + w4[r].w * s4[c].w;
            }
#pragma unroll
            for (int r = 0; r < 4; r++)
#pragma unroll
                for (int c = 0; c < 2; c++) sM[(i0 + r) * 32 + dd0 + c] -= acc[r][c];
        }
        __syncthreads();

        // P2: stage Qd over Wm
        for (int idx = tid; idx < CH * DH / 8; idx += 256)
            b8ld(qc + (size_t)idx * 8, &sWQ[idx * 8]);
        __syncthreads();

        // P3: O = Qd@S^T + W2@mid ; store fp32 to O (B,H,L,Dh) in d_out
        {
            int ib = tid >> 4, db = tid & 15;
            int i0 = ib * 4, dd0 = db * 2;
            float acc[4][2];
#pragma unroll
            for (int r = 0; r < 4; r++) { acc[r][0] = 0.0f; acc[r][1] = 0.0f; }
            for (int e = 0; e < DH; e += 4) {
                float4 q4[4], s4[2];
#pragma unroll
                for (int r = 0; r < 4; r++) q4[r] = *(const float4*)&sWQ[(i0 + r) * DH + e];
#pragma unroll
                for (int c = 0; c < 2; c++) s4[c] = *(const float4*)&sS[(dd0 + c) * DH + e];
#pragma unroll
                for (int r = 0; r < 4; r++)
#pragma unroll
                    for (int c = 0; c < 2; c++)
                        acc[r][c] += q4[r].x * s4[c].x + q4[r].y * s4[c].y + q4[r].z * s4[c].z + q4[r].w * s4[c].w;
            }
            for (int j = 0; j < CH; j += 4) {
                float wq[4][4];
#pragma unroll
                for (int r = 0; r < 4; r++) {
                    float4 t = *(const float4*)(w2c + (size_t)(i0 + r) * CH + j);
                    wq[r][0] = t.x; wq[r][1] = t.y; wq[r][2] = t.z; wq[r][3] = t.w;
                }
#pragma unroll
                for (int s = 0; s < 4; s++) {
                    float2 mm = *(const float2*)&sM[(j + s) * 32 + dd0];
#pragma unroll
                    for (int r = 0; r < 4; r++) {
                        acc[r][0] += wq[r][s] * mm.x;
                        acc[r][1] += wq[r][s] * mm.y;
                    }
                }
            }
#pragma unroll
            for (int r = 0; r < 4; r++) {
                float2 st;
                st.x = acc[r][0]; st.y = acc[r][1];
                *(float2*)(Og + ((size_t)bh * L_ + (size_t)n * CH + i0 + r) * DH + d0 + dd0) = st;
            }
        }
        __syncthreads();

        // P4: S = gC*S + mid^T @ Kd (2d x 8e per thread; Kd streamed bf16)
        {
            int db2 = tid >> 4, eb = tid & 15;
            int dd0 = db2 * 2, e0 = eb * 8;
            float acc[2][8];
#pragma unroll
            for (int c = 0; c < 2; c++)
#pragma unroll
                for (int ee = 0; ee < 8; ee++) acc[c][ee] = 0.0f;
            for (int i = 0; i < CH; i += 4) {
#pragma unroll
                for (int s = 0; s < 4; s++) {
                    float2 mm = *(const float2*)&sM[(i + s) * 32 + dd0];
                    float kk[8];
                    b8ld(kc + (size_t)(i + s) * DH + e0, kk);
#pragma unroll
                    for (int ee = 0; ee < 8; ee++) {
                        acc[0][ee] += mm.x * kk[ee];
                        acc[1][ee] += mm.y * kk[ee];
                    }
                }
            }
#pragma unroll
            for (int c = 0; c < 2; c++)
#pragma unroll
                for (int ee = 0; ee < 8; ee++) {
                    int idx = (dd0 + c) * DH + e0 + ee;
                    sS[idx] = gC * sS[idx] + acc[c][ee];
                }
        }
        __syncthreads();
    }

    for (int idx = tid; idx < 32 * DH; idx += 256)
        Sfin[(size_t)bh * DH * DH + (size_t)(d0 + (idx >> 7)) * DH + (idx & 127)] = sS[idx];
}

// RMSNorm over Dh * norm_w * SiLU(gate); transposes (B,H,L,Dh)->(B,L,H*Dh)
__global__ __launch_bounds__(256) void epilogue_gate(const float* __restrict__ Ob,
                                                     const u16* __restrict__ gpre,
                                                     const float* __restrict__ norm_w,
                                                     u16* __restrict__ gated) {
    int wid = blockIdx.x * 4 + (threadIdx.x >> 6);
    int lane = threadIdx.x & 63;
    int l = wid & (L_ - 1);
    int bh = wid >> 12;
    int b = bh >> 4, h = bh & 15;
    const float* orow = Ob + ((size_t)bh * L_ + l) * DH;
    float o0 = orow[lane], o1 = orow[lane + 64];
    float ss = o0 * o0 + o1 * o1;
#pragma unroll
    for (int m = 32; m >= 1; m >>= 1) ss += __shfl_xor(ss, m, 64);
    float r = rsqrtf(ss * (1.0f / 128.0f) + 1e-5f);
    size_t gidx = ((size_t)b * L_ + l) * HD + h * DH;
    float gp0 = b2f(gpre[gidx + lane]), gp1 = b2f(gpre[gidx + lane + 64]);
    gated[gidx + lane] = f2b(o0 * r * norm_w[lane] * (gp0 * sigm(gp0)));
    gated[gidx + lane + 64] = f2b(o1 * r * norm_w[lane + 64] * (gp1 * sigm(gp1)));
}

// ---------------------------------------------------------------------------
extern "C" void kernel_launch(void* const* d_in, const int* in_sizes, int n_in,
                              void* d_out, int out_size, void* d_ws, size_t ws_size,
                              hipStream_t stream) {
    const float* x       = (const float*)d_in[0];
    const float* Wq      = (const float*)d_in[1];
    const float* Wk      = (const float*)d_in[2];
    const float* Wv      = (const float*)d_in[3];
    const float* Wb      = (const float*)d_in[4];
    const float* Wa      = (const float*)d_in[5];
    const float* A_log   = (const float*)d_in[6];
    const float* dt_bias = (const float*)d_in[7];
    const float* conv_q  = (const float*)d_in[8];
    const float* conv_k  = (const float*)d_in[9];
    const float* conv_v  = (const float*)d_in[10];
    const float* Wg      = (const float*)d_in[11];
    const float* norm_w  = (const float*)d_in[12];
    const float* Wo      = (const float*)d_in[13];
    const float* S0      = (const float*)d_in[14];
    float* out = (float*)d_out;

    // Workspace layout: 4 bf16 PSZ tensors + fp32 W2 + smalls = ~162 MB.
    // Pb: pre-activation scratch (q/k/v/g pre) AND Wm (disjoint lifetimes).
    // Qb: q -> Qd -> gated.  Kb: k -> Kd.  Vb: v -> U.
    // O tensor (fp32) lives in d_out[0:PSZ]; final GEMM overwrites it after
    // the epilogue consumes it (stream-ordered).
    u16* Pb = (u16*)d_ws;
    u16* Qb = Pb + PSZ;
    u16* Kb = Qb + PSZ;
    u16* Vb = Kb + PSZ;
    float* w2   = (float*)(Vb + PSZ);   // 2048 * 64 * 64 fp32 = 32 MB
    float* bpre = w2 + 8388608;
    float* apre = bpre + BHL;
    float* betab = apre + BHL;
    float* gbuf = betab + BHL;
    float* gamC = gbuf + BHL;           // BH*NCH = 2048

    float* Obuf = out;                  // (B,H,L,Dh) fp32, PSZ elements
    float* Sfin = out + PSZ;

    dim3 gblk(16, 64);  // (N/128, M/128) for 8192x2048 GEMMs

    gemm_nt<float, u16><<<gblk, 256, 0, stream>>>(x, Wq, Pb, 8192, 2048, 2048);
    conv_silu_norm<<<32768, 256, 0, stream>>>(Pb, conv_q, Qb, 0);
    gemm_nt<float, u16><<<gblk, 256, 0, stream>>>(x, Wk, Pb, 8192, 2048, 2048);
    conv_silu_norm<<<32768, 256, 0, stream>>>(Pb, conv_k, Kb, 1);
    gemm_nt<float, u16><<<gblk, 256, 0, stream>>>(x, Wv, Pb, 8192, 2048, 2048);
    conv_silu_norm<<<32768, 256, 0, stream>>>(Pb, conv_v, Vb, 2);
    proj_small<<<8192, 64, 0, stream>>>(x, Wb, Wa, bpre, apre);
    beta_g_k<<<512, 256, 0, stream>>>(bpre, apre, A_log, dt_bias, betab, gbuf);
    prep_chunks<<<2048, 256, 0, stream>>>(Qb, Kb, Vb, betab, gbuf, Pb, w2, gamC);
    scan_seq<<<128, 256, 0, stream>>>(Pb, Vb, Qb, Kb, w2, gamC, S0, Obuf, Sfin);
    gemm_nt<float, u16><<<gblk, 256, 0, stream>>>(x, Wg, Pb, 8192, 2048, 2048);
    epilogue_gate<<<32768, 256, 0, stream>>>(Obuf, Pb, norm_w, Qb);
    gemm_nt<u16, float><<<gblk, 256, 0, stream>>>(Qb, Wo, out, 8192, 2048, 2048);
}

// Round 3
// 2034.111 us; speedup vs baseline: 3.3698x; 3.3698x over previous
//
#include <hip/hip_runtime.h>
#include <math.h>

// GatedDeltaNet forward, MI355X round 2: MFMA GEMMs + MFMA chunk scan.
// B=2 L=4096 D=2048 H=16 Dh=128 C=64 KW=4
#define B_   2
#define L_   4096
#define D_   2048
#define H_   16
#define DH   128
#define CH   64
#define NCH  64
#define HD   2048
#define BH   32
#define BHL  131072
#define PSZ  16777216ull

typedef unsigned short u16;
typedef __attribute__((ext_vector_type(8))) short bf16x8;
typedef __attribute__((ext_vector_type(4))) float f32x4;
#define MFMA16(a, b, c) __builtin_amdgcn_mfma_f32_16x16x32_bf16(a, b, c, 0, 0, 0)

static __device__ __forceinline__ float sigm(float x) { return 1.0f / (1.0f + expf(-x)); }

static __device__ __forceinline__ float b2f(u16 u) {
    union { float f; unsigned int i; } v; v.i = ((unsigned int)u) << 16; return v.f;
}
static __device__ __forceinline__ u16 f2b(float f) {
    union { float f; unsigned int i; } v; v.f = f;
    unsigned int r = v.i + 0x7fffu + ((v.i >> 16) & 1u);
    return (u16)(r >> 16);
}
static __device__ __forceinline__ void b8ld(const u16* p, float* d) {
    uint4 u = *(const uint4*)p;
    d[0] = b2f((u16)(u.x & 0xffff)); d[1] = b2f((u16)(u.x >> 16));
    d[2] = b2f((u16)(u.y & 0xffff)); d[3] = b2f((u16)(u.y >> 16));
    d[4] = b2f((u16)(u.z & 0xffff)); d[5] = b2f((u16)(u.z >> 16));
    d[6] = b2f((u16)(u.w & 0xffff)); d[7] = b2f((u16)(u.w >> 16));
}
static __device__ __forceinline__ void b8st(const float* s, u16* p) {
    uint4 u;
    u.x = (unsigned)f2b(s[0]) | ((unsigned)f2b(s[1]) << 16);
    u.y = (unsigned)f2b(s[2]) | ((unsigned)f2b(s[3]) << 16);
    u.z = (unsigned)f2b(s[4]) | ((unsigned)f2b(s[5]) << 16);
    u.w = (unsigned)f2b(s[6]) | ((unsigned)f2b(s[7]) << 16);
    *(uint4*)p = u;
}
static __device__ __forceinline__ float4 ldA4(const u16* p) {
    ushort4 u = *(const ushort4*)p;
    float4 f; f.x = b2f(u.x); f.y = b2f(u.y); f.z = b2f(u.z); f.w = b2f(u.w); return f;
}

// staging: 8 elements global -> bf16 LDS (16B write)
static __device__ __forceinline__ void stage8(const u16* g, u16* l) {
    *(uint4*)l = *(const uint4*)g;
}
static __device__ __forceinline__ void stage8(const float* g, u16* l) {
    float4 a = *(const float4*)g, b = *(const float4*)(g + 4);
    u16 t[8] = {f2b(a.x), f2b(a.y), f2b(a.z), f2b(a.w),
                f2b(b.x), f2b(b.y), f2b(b.z), f2b(b.w)};
    *(uint4*)l = *(uint4*)t;
}
static __device__ __forceinline__ void cstore(float* p, float v) { *p = v; }
static __device__ __forceinline__ void cstore(u16* p, float v) { *p = f2b(v); }

// ---------------------------------------------------------------------------
// MFMA GEMM: C[M,N] = A[M,K] @ B[N,K]^T, fp32 accumulate.
// 128x128 tile, BK=64, 256 thr (4 waves, each 64x64 quadrant, 4x4 16x16 tiles).
// LDS rows padded to 72 bf16 (144B == 36 banks => 2-way conflict, free).
// ---------------------------------------------------------------------------
template <typename TA, typename TB, typename TC>
__global__ __launch_bounds__(256) void gemm_bt_mfma(const TA* __restrict__ A,
                                                    const TB* __restrict__ Bm,
                                                    TC* __restrict__ Cm,
                                                    int M, int N, int K) {
    __shared__ __align__(16) u16 sA[128 * 72];
    __shared__ __align__(16) u16 sB[128 * 72];
    const int tid = threadIdx.x;
    const int w = tid >> 6, lane = tid & 63, lq = lane >> 4, ln = lane & 15;
    const int wm = w >> 1, wn = w & 1;
    const int mbase = blockIdx.y * 128, nbase = blockIdx.x * 128;

    f32x4 acc[4][4];
#pragma unroll
    for (int mt = 0; mt < 4; mt++)
#pragma unroll
        for (int nt = 0; nt < 4; nt++) acc[mt][nt] = (f32x4){0.f, 0.f, 0.f, 0.f};

    for (int k0 = 0; k0 < K; k0 += 64) {
#pragma unroll
        for (int j = 0; j < 4; j++) {
            int f = tid + 256 * j;
            int row = f >> 3, kc = (f & 7) * 8;
            stage8(A + (size_t)(mbase + row) * K + k0 + kc, &sA[row * 72 + kc]);
            stage8(Bm + (size_t)(nbase + row) * K + k0 + kc, &sB[row * 72 + kc]);
        }
        __syncthreads();
#pragma unroll
        for (int ks = 0; ks < 2; ks++) {
            bf16x8 af[4], bfr[4];
#pragma unroll
            for (int mt = 0; mt < 4; mt++)
                af[mt] = *(const bf16x8*)&sA[(wm * 64 + mt * 16 + ln) * 72 + ks * 32 + lq * 8];
#pragma unroll
            for (int nt = 0; nt < 4; nt++)
                bfr[nt] = *(const bf16x8*)&sB[(wn * 64 + nt * 16 + ln) * 72 + ks * 32 + lq * 8];
#pragma unroll
            for (int mt = 0; mt < 4; mt++)
#pragma unroll
                for (int nt = 0; nt < 4; nt++)
                    acc[mt][nt] = MFMA16(af[mt], bfr[nt], acc[mt][nt]);
        }
        __syncthreads();
    }
#pragma unroll
    for (int mt = 0; mt < 4; mt++)
#pragma unroll
        for (int nt = 0; nt < 4; nt++) {
            int col = nbase + wn * 64 + nt * 16 + ln;
#pragma unroll
            for (int r = 0; r < 4; r++) {
                int row = mbase + wm * 64 + mt * 16 + lq * 4 + r;
                cstore(Cm + (size_t)row * N + col, acc[mt][nt][r]);
            }
        }
}

// ---------------------------------------------------------------------------
// Causal depthwise conv (KW=4) + SiLU + optional L2 norm over Dh.
// ---------------------------------------------------------------------------
__global__ __launch_bounds__(256) void conv_silu_norm(const u16* __restrict__ pre,
                                                      const float* __restrict__ w,
                                                      u16* __restrict__ out, int mode) {
    int wid = blockIdx.x * 4 + (threadIdx.x >> 6);
    int lane = threadIdx.x & 63;
    int l = wid & (L_ - 1);
    int bh = wid >> 12;
    int b = bh >> 4, h = bh & 15;

    float vals[2];
    float sumsq = 0.0f;
#pragma unroll
    for (int s = 0; s < 2; s++) {
        int d = lane + 64 * s;
        int c = h * DH + d;
        const u16* col = pre + (size_t)b * L_ * HD + c;
        float acc = 0.0f;
        if (l >= 3) {
            acc = w[c * 4 + 0] * b2f(col[(size_t)(l - 3) * HD]) +
                  w[c * 4 + 1] * b2f(col[(size_t)(l - 2) * HD]) +
                  w[c * 4 + 2] * b2f(col[(size_t)(l - 1) * HD]) +
                  w[c * 4 + 3] * b2f(col[(size_t)l * HD]);
        } else {
#pragma unroll
            for (int j = 0; j < 4; j++) {
                int ll = l - 3 + j;
                if (ll >= 0) acc += w[c * 4 + j] * b2f(col[(size_t)ll * HD]);
            }
        }
        float y = acc * sigm(acc);
        vals[s] = y;
        sumsq += y * y;
    }
    if (mode < 2) {
#pragma unroll
        for (int m = 32; m >= 1; m >>= 1) sumsq += __shfl_xor(sumsq, m, 64);
        float scale = 1.0f / fmaxf(sqrtf(sumsq), 1e-12f);
        if (mode == 0) scale *= 0.08838834764831843f;
        vals[0] *= scale;
        vals[1] *= scale;
    }
    u16* o = out + ((size_t)bh * L_ + l) * DH;
    o[lane] = f2b(vals[0]);
    o[lane + 64] = f2b(vals[1]);
}

__global__ __launch_bounds__(64) void proj_small(const float* __restrict__ x,
                                                 const float* __restrict__ Wb,
                                                 const float* __restrict__ Wa,
                                                 float* __restrict__ bpre,
                                                 float* __restrict__ apre) {
    int row = blockIdx.x;
    int lane = threadIdx.x;
    const float* xr = x + (size_t)row * D_;
    float xv[32];
#pragma unroll
    for (int j = 0; j < 32; j++) xv[j] = xr[lane + 64 * j];
    for (int h = 0; h < 16; h++) {
        const float* wr = Wb + (size_t)h * D_;
        float acc = 0.0f;
#pragma unroll
        for (int j = 0; j < 32; j++) acc += xv[j] * wr[lane + 64 * j];
#pragma unroll
        for (int m = 32; m >= 1; m >>= 1) acc += __shfl_xor(acc, m, 64);
        if (lane == 0) bpre[(size_t)row * 16 + h] = acc;
    }
    for (int h = 0; h < 16; h++) {
        const float* wr = Wa + (size_t)h * D_;
        float acc = 0.0f;
#pragma unroll
        for (int j = 0; j < 32; j++) acc += xv[j] * wr[lane + 64 * j];
#pragma unroll
        for (int m = 32; m >= 1; m >>= 1) acc += __shfl_xor(acc, m, 64);
        if (lane == 0) apre[(size_t)row * 16 + h] = acc;
    }
}

__global__ __launch_bounds__(256) void beta_g_k(const float* __restrict__ bpre,
                                                const float* __restrict__ apre,
                                                const float* __restrict__ A_log,
                                                const float* __restrict__ dt_bias,
                                                float* __restrict__ beta, float* __restrict__ g) {
    int gi = blockIdx.x * 256 + threadIdx.x;
    int l = gi & (L_ - 1);
    int bh = gi >> 12;
    int b = bh >> 4, h = bh & 15;
    float bp = bpre[((size_t)b * L_ + l) * 16 + h];
    float ap = apre[((size_t)b * L_ + l) * 16 + h] + dt_bias[h];
    float sp = (ap > 20.0f) ? ap : log1pf(expf(ap));
    beta[(size_t)bh * L_ + l] = 1.0f / (1.0f + expf(-bp));
    g[(size_t)bh * L_ + l] = -expf(A_log[h]) * sp;
}

// ---------------------------------------------------------------------------
// Per-chunk prep (2048 blocks). W2 now bf16.
// ---------------------------------------------------------------------------
__global__ __launch_bounds__(256) void prep_chunks(u16* __restrict__ q, u16* __restrict__ k,
                                                   u16* __restrict__ v,
                                                   const float* __restrict__ beta,
                                                   const float* __restrict__ g,
                                                   u16* __restrict__ Wm, u16* __restrict__ W2,
                                                   float* __restrict__ gamC) {
    __shared__ __align__(16) float sK[CH * DH];
    __shared__ __align__(16) float sA[CH * CH];
    __shared__ float sLg[CH], sGam[CH], sGcr[CH], sBeta[CH];

    const int cid = blockIdx.x;
    const int bh = cid >> 6, n = cid & 63;
    const int tid = threadIdx.x;
    const size_t cbase = ((size_t)bh * L_ + (size_t)n * CH) * DH;
    u16* qw = q + cbase;
    u16* kw = k + cbase;
    const u16* vc = v + cbase;

    if (tid < 64) {
        float lg = g[(size_t)bh * L_ + (size_t)n * CH + tid];
#pragma unroll
        for (int off = 1; off < 64; off <<= 1) {
            float u = __shfl_up(lg, off, 64);
            if (tid >= off) lg += u;
        }
        float lgC = __shfl(lg, 63, 64);
        sLg[tid] = lg;
        sGam[tid] = expf(lg);
        sGcr[tid] = expf(lgC - lg);
        sBeta[tid] = beta[(size_t)bh * L_ + (size_t)n * CH + tid];
        if (tid == 63) gamC[cid] = expf(lgC);
    }
    for (int idx = tid; idx < CH * DH / 8; idx += 256)
        b8ld(kw + (size_t)idx * 8, &sK[idx * 8]);
    __syncthreads();

    {
        int bi = tid >> 4, bj = tid & 15;
        int i0 = bi * 4, j0 = bj * 4;
        u16* w2c = W2 + (size_t)cid * CH * CH;
        if (bi >= bj) {
            float dotA[4][4], dotQ[4][4];
#pragma unroll
            for (int r = 0; r < 4; r++)
#pragma unroll
                for (int c = 0; c < 4; c++) { dotA[r][c] = 0.0f; dotQ[r][c] = 0.0f; }
            for (int e = 0; e < DH; e += 4) {
                float4 ka[4], kb[4], qa[4];
#pragma unroll
                for (int r = 0; r < 4; r++) {
                    ka[r] = *(const float4*)&sK[(i0 + r) * DH + e];
                    qa[r] = ldA4(qw + (size_t)(i0 + r) * DH + e);
                }
#pragma unroll
                for (int c = 0; c < 4; c++) kb[c] = *(const float4*)&sK[(j0 + c) * DH + e];
#pragma unroll
                for (int r = 0; r < 4; r++)
#pragma unroll
                    for (int c = 0; c < 4; c++) {
                        dotA[r][c] += ka[r].x * kb[c].x + ka[r].y * kb[c].y + ka[r].z * kb[c].z + ka[r].w * kb[c].w;
                        dotQ[r][c] += qa[r].x * kb[c].x + qa[r].y * kb[c].y + qa[r].z * kb[c].z + qa[r].w * kb[c].w;
                    }
            }
#pragma unroll
            for (int r = 0; r < 4; r++)
#pragma unroll
                for (int c = 0; c < 4; c++) {
                    int i = i0 + r, j = j0 + c;
                    float dexp = expf(sLg[i] - sLg[j]);
                    sA[i * CH + j] = (j < i) ? sBeta[i] * dexp * dotA[r][c] : ((j == i) ? 1.0f : 0.0f);
                    w2c[i * CH + j] = f2b((j <= i) ? dotQ[r][c] * dexp : 0.0f);
                }
        } else {
#pragma unroll
            for (int r = 0; r < 4; r++)
#pragma unroll
                for (int c = 0; c < 4; c++) {
                    sA[(i0 + r) * CH + j0 + c] = 0.0f;
                    w2c[(i0 + r) * CH + j0 + c] = 0;
                }
        }
    }
    __syncthreads();

    for (int idx = tid; idx < CH * DH; idx += 256) {
        int i = idx >> 7;
        qw[idx] = f2b(b2f(qw[idx]) * sGam[i]);
        kw[idx] = f2b(b2f(kw[idx]) * sGcr[i]);
        sK[idx] *= sBeta[i] * sGam[i];
    }
    __syncthreads();

    for (int i = 1; i < 64; i++) {
        float xj = 0.0f;
        bool act = (tid < i);
        if (act) {
            float acc2 = 0.0f;
            for (int kk = 0; kk < i; kk++) acc2 += sA[i * CH + kk] * sA[kk * CH + tid];
            xj = -acc2;
        }
        __syncthreads();
        if (act) sA[i * CH + tid] = xj;
        __syncthreads();
    }

    {
        int ib = tid >> 4, cb = tid & 15;
        int i0 = ib * 4, c0 = cb * 8;
        float accK[4][8], accV[4][8];
#pragma unroll
        for (int r = 0; r < 4; r++)
#pragma unroll
            for (int c = 0; c < 8; c++) { accK[r][c] = 0.0f; accV[r][c] = 0.0f; }
        for (int kk = 0; kk < CH; kk += 4) {
            float tr[4][4];
#pragma unroll
            for (int r = 0; r < 4; r++) {
                float4 t4 = *(const float4*)&sA[(i0 + r) * CH + kk];
                tr[r][0] = t4.x; tr[r][1] = t4.y; tr[r][2] = t4.z; tr[r][3] = t4.w;
            }
#pragma unroll
            for (int s = 0; s < 4; s++) {
                int kks = kk + s;
                float va[8], ka[8];
                b8ld(vc + (size_t)kks * DH + c0, va);
                float bv = sBeta[kks];
#pragma unroll
                for (int c = 0; c < 8; c++) { va[c] *= bv; ka[c] = sK[kks * DH + c0 + c]; }
#pragma unroll
                for (int r = 0; r < 4; r++) {
                    float t = tr[r][s];
#pragma unroll
                    for (int c = 0; c < 8; c++) {
                        accK[r][c] += t * ka[c];
                        accV[r][c] += t * va[c];
                    }
                }
            }
        }
        u16* wmc = Wm + (size_t)cid * CH * DH;
#pragma unroll
        for (int r = 0; r < 4; r++) b8st(&accK[r][0], wmc + (size_t)(i0 + r) * DH + c0);
        __syncthreads();
        u16* uc = v + cbase;
#pragma unroll
        for (int r = 0; r < 4; r++) b8st(&accV[r][0], uc + (size_t)(i0 + r) * DH + c0);
    }
}

// ---------------------------------------------------------------------------
// MFMA inter-chunk scan. Grid = BH * 8 d-groups (16 d-rows each) = 256 blocks.
// S state in fp32 MFMA accumulators (2 16x16 tiles per wave; wave w owns
// e in [w*32, w*32+32)). Per chunk:
//   G1: mid(64x16) = U - Wm(64x128) @ S^T       (S dumped to bf16 LDS)
//   G2: O(64x16)   = Qd @ S^T + W2(64x64) @ mid
//   G3: S(16x128)  = gamC*S + mid^T(16x64) @ Kd (Kd transposed at staging)
// All LDS rows padded: stride%32banks == 4 => 2-way conflicts only (free).
// ---------------------------------------------------------------------------
__global__ __launch_bounds__(256) void scan_mfma(const u16* __restrict__ Wm,
                                                 const u16* __restrict__ U,
                                                 const u16* __restrict__ Qd,
                                                 const u16* __restrict__ Kd,
                                                 const u16* __restrict__ W2,
                                                 const float* __restrict__ gamC,
                                                 const float* __restrict__ S0,
                                                 float* __restrict__ Og,
                                                 float* __restrict__ Sfin) {
    __shared__ __align__(16) u16 sWm[64 * 136];
    __shared__ __align__(16) u16 sQd[64 * 136];
    __shared__ __align__(16) u16 sKdT[128 * 72];
    __shared__ __align__(16) u16 sW2[64 * 72];
    __shared__ __align__(16) u16 sS[16 * 136];
    __shared__ __align__(16) u16 sMidT[16 * 72];

    const int bid = blockIdx.x;
    const int bh = bid >> 3, dg = bid & 7, d0 = dg * 16;
    const int tid = threadIdx.x;
    const int w = tid >> 6, lane = tid & 63, lq = lane >> 4, ln = lane & 15;

    // S tiles: d = lq*4 + r (local, 0..15), e = w*32 + t2*16 + ln
    f32x4 S_t[2];
#pragma unroll
    for (int t2 = 0; t2 < 2; t2++)
#pragma unroll
        for (int r = 0; r < 4; r++)
            S_t[t2][r] = S0[(size_t)bh * DH * DH + (size_t)(d0 + lq * 4 + r) * DH + w * 32 + t2 * 16 + ln];

    for (int n = 0; n < NCH; n++) {
        const size_t cid = (size_t)bh * NCH + n;
        const u16* wmc = Wm + cid * CH * DH;
        const size_t tb = ((size_t)bh * L_ + (size_t)n * CH) * DH;
        const u16* uc = U + tb;
        const u16* qc = Qd + tb;
        const u16* kc = Kd + tb;
        const u16* w2c = W2 + cid * CH * CH;
        const float gC = gamC[cid];

        // dump S -> bf16 LDS [d][e] (stride 136)
#pragma unroll
        for (int t2 = 0; t2 < 2; t2++)
#pragma unroll
            for (int r = 0; r < 4; r++)
                sS[(lq * 4 + r) * 136 + w * 32 + t2 * 16 + ln] = f2b(S_t[t2][r]);

        // stage Wm, Qd (64x128, stride 136), W2 (64x64, stride 72)
#pragma unroll
        for (int j = 0; j < 4; j++) {
            int f = tid + 256 * j;           // 1024 ushort8 units
            int row = f >> 4, kc8 = (f & 15) * 8;
            *(uint4*)&sWm[row * 136 + kc8] = *(const uint4*)(wmc + f * 8);
            *(uint4*)&sQd[row * 136 + kc8] = *(const uint4*)(qc + f * 8);
        }
#pragma unroll
        for (int j = 0; j < 2; j++) {
            int f = tid + 256 * j;           // 512 ushort8 units
            int row = f >> 3, c8 = (f & 7) * 8;
            *(uint4*)&sW2[row * 72 + c8] = *(const uint4*)(w2c + f * 8);
        }
        // stage Kd transposed: sKdT[e][i] (stride 72)
#pragma unroll
        for (int rep = 0; rep < 8; rep++) {
            int f = tid + 256 * rep;         // 2048 ushort4 units
            int i = f >> 5, e4 = (f & 31) * 4;
            ushort4 vv = *(const ushort4*)(kc + (size_t)f * 4);
            sKdT[(e4 + 0) * 72 + i] = vv.x;
            sKdT[(e4 + 1) * 72 + i] = vv.y;
            sKdT[(e4 + 2) * 72 + i] = vv.z;
            sKdT[(e4 + 3) * 72 + i] = vv.w;
        }
        __syncthreads();

        // G1: mid = U - Wm @ S^T  (wave w: i-tile rows w*16..w*16+16)
        f32x4 macc = (f32x4){0.f, 0.f, 0.f, 0.f};
#pragma unroll
        for (int ks = 0; ks < 4; ks++) {
            bf16x8 a = *(const bf16x8*)&sWm[(w * 16 + ln) * 136 + ks * 32 + lq * 8];
            bf16x8 b = *(const bf16x8*)&sS[ln * 136 + ks * 32 + lq * 8];
            macc = MFMA16(a, b, macc);
        }
#pragma unroll
        for (int r = 0; r < 4; r++) {
            int i = w * 16 + lq * 4 + r;
            float mv = b2f(uc[(size_t)i * DH + d0 + ln]) - macc[r];
            sMidT[ln * 72 + i] = f2b(mv);
        }
        __syncthreads();

        // G2: O = Qd @ S^T + W2 @ mid
        f32x4 oacc = (f32x4){0.f, 0.f, 0.f, 0.f};
#pragma unroll
        for (int ks = 0; ks < 4; ks++) {
            bf16x8 a = *(const bf16x8*)&sQd[(w * 16 + ln) * 136 + ks * 32 + lq * 8];
            bf16x8 b = *(const bf16x8*)&sS[ln * 136 + ks * 32 + lq * 8];
            oacc = MFMA16(a, b, oacc);
        }
#pragma unroll
        for (int ks = 0; ks < 2; ks++) {
            bf16x8 a = *(const bf16x8*)&sW2[(w * 16 + ln) * 72 + ks * 32 + lq * 8];
            bf16x8 b = *(const bf16x8*)&sMidT[ln * 72 + ks * 32 + lq * 8];
            oacc = MFMA16(a, b, oacc);
        }
#pragma unroll
        for (int r = 0; r < 4; r++) {
            int i = w * 16 + lq * 4 + r;
            Og[((size_t)bh * L_ + (size_t)n * CH + i) * DH + d0 + ln] = oacc[r];
        }

        // G3: S = gC*S + mid^T @ Kd
#pragma unroll
        for (int t2 = 0; t2 < 2; t2++)
#pragma unroll
            for (int r = 0; r < 4; r++) S_t[t2][r] *= gC;
#pragma unroll
        for (int ks = 0; ks < 2; ks++) {
            bf16x8 a = *(const bf16x8*)&sMidT[ln * 72 + ks * 32 + lq * 8];
#pragma unroll
            for (int t2 = 0; t2 < 2; t2++) {
                bf16x8 b = *(const bf16x8*)&sKdT[((2 * w + t2) * 16 + ln) * 72 + ks * 32 + lq * 8];
                S_t[t2] = MFMA16(a, b, S_t[t2]);
            }
        }
        __syncthreads();
    }

#pragma unroll
    for (int t2 = 0; t2 < 2; t2++)
#pragma unroll
        for (int r = 0; r < 4; r++)
            Sfin[(size_t)bh * DH * DH + (size_t)(d0 + lq * 4 + r) * DH + w * 32 + t2 * 16 + ln] = S_t[t2][r];
}

__global__ __launch_bounds__(256) void epilogue_gate(const float* __restrict__ Ob,
                                                     const u16* __restrict__ gpre,
                                                     const float* __restrict__ norm_w,
                                                     u16* __restrict__ gated) {
    int wid = blockIdx.x * 4 + (threadIdx.x >> 6);
    int lane = threadIdx.x & 63;
    int l = wid & (L_ - 1);
    int bh = wid >> 12;
    int b = bh >> 4, h = bh & 15;
    const float* orow = Ob + ((size_t)bh * L_ + l) * DH;
    float o0 = orow[lane], o1 = orow[lane + 64];
    float ss = o0 * o0 + o1 * o1;
#pragma unroll
    for (int m = 32; m >= 1; m >>= 1) ss += __shfl_xor(ss, m, 64);
    float r = rsqrtf(ss * (1.0f / 128.0f) + 1e-5f);
    size_t gidx = ((size_t)b * L_ + l) * HD + h * DH;
    float gp0 = b2f(gpre[gidx + lane]), gp1 = b2f(gpre[gidx + lane + 64]);
    gated[gidx + lane] = f2b(o0 * r * norm_w[lane] * (gp0 * sigm(gp0)));
    gated[gidx + lane + 64] = f2b(o1 * r * norm_w[lane + 64] * (gp1 * sigm(gp1)));
}

// ---------------------------------------------------------------------------
extern "C" void kernel_launch(void* const* d_in, const int* in_sizes, int n_in,
                              void* d_out, int out_size, void* d_ws, size_t ws_size,
                              hipStream_t stream) {
    const float* x       = (const float*)d_in[0];
    const float* Wq      = (const float*)d_in[1];
    const float* Wk      = (const float*)d_in[2];
    const float* Wv      = (const float*)d_in[3];
    const float* Wb      = (const float*)d_in[4];
    const float* Wa      = (const float*)d_in[5];
    const float* A_log   = (const float*)d_in[6];
    const float* dt_bias = (const float*)d_in[7];
    const float* conv_q  = (const float*)d_in[8];
    const float* conv_k  = (const float*)d_in[9];
    const float* conv_v  = (const float*)d_in[10];
    const float* Wg      = (const float*)d_in[11];
    const float* norm_w  = (const float*)d_in[12];
    const float* Wo      = (const float*)d_in[13];
    const float* S0      = (const float*)d_in[14];
    float* out = (float*)d_out;

    // Workspace (~146 MB): Pb (preact -> Wm -> gpre), Qb (q->Qd->gated),
    // Kb (k->Kd), Vb (v->U), W2b bf16, smalls. O fp32 lives in d_out[0:PSZ].
    u16* Pb = (u16*)d_ws;
    u16* Qb = Pb + PSZ;
    u16* Kb = Qb + PSZ;
    u16* Vb = Kb + PSZ;
    u16* W2b = Vb + PSZ;                       // 8388608 u16
    float* bpre = (float*)(W2b + 8388608);
    float* apre = bpre + BHL;
    float* betab = apre + BHL;
    float* gbuf = betab + BHL;
    float* gamC = gbuf + BHL;                  // 2048

    float* Obuf = out;
    float* Sfin = out + PSZ;

    dim3 gblk(16, 64);  // (N/128, M/128)

    gemm_bt_mfma<float, float, u16><<<gblk, 256, 0, stream>>>(x, Wq, Pb, 8192, 2048, 2048);
    conv_silu_norm<<<32768, 256, 0, stream>>>(Pb, conv_q, Qb, 0);
    gemm_bt_mfma<float, float, u16><<<gblk, 256, 0, stream>>>(x, Wk, Pb, 8192, 2048, 2048);
    conv_silu_norm<<<32768, 256, 0, stream>>>(Pb, conv_k, Kb, 1);
    gemm_bt_mfma<float, float, u16><<<gblk, 256, 0, stream>>>(x, Wv, Pb, 8192, 2048, 2048);
    conv_silu_norm<<<32768, 256, 0, stream>>>(Pb, conv_v, Vb, 2);
    proj_small<<<8192, 64, 0, stream>>>(x, Wb, Wa, bpre, apre);
    beta_g_k<<<512, 256, 0, stream>>>(bpre, apre, A_log, dt_bias, betab, gbuf);
    prep_chunks<<<2048, 256, 0, stream>>>(Qb, Kb, Vb, betab, gbuf, Pb, W2b, gamC);
    scan_mfma<<<256, 256, 0, stream>>>(Pb, Vb, Qb, Kb, W2b, gamC, S0, Obuf, Sfin);
    gemm_bt_mfma<float, float, u16><<<gblk, 256, 0, stream>>>(x, Wg, Pb, 8192, 2048, 2048);
    epilogue_gate<<<32768, 256, 0, stream>>>(Obuf, Pb, norm_w, Qb);
    gemm_bt_mfma<u16, float, float><<<gblk, 256, 0, stream>>>(Qb, Wo, out, 8192, 2048, 2048);
}

// Round 4
// 1338.413 us; speedup vs baseline: 5.1213x; 1.5198x over previous
//
#include <hip/hip_runtime.h>
#include <math.h>

// GatedDeltaNet forward, MI355X round 4: async (global_load_lds) bf16 MFMA
// GEMMs with XOR-swizzled LDS, pre-converted bf16 x/weights, reordered
// pipeline (g-GEMM after scan so gpre reuses the U buffer). ~195 MB ws.
// B=2 L=4096 D=2048 H=16 Dh=128 C=64 KW=4
#define B_   2
#define L_   4096
#define D_   2048
#define H_   16
#define DH   128
#define CH   64
#define NCH  64
#define HD   2048
#define BH   32
#define BHL  131072
#define PSZ  16777216ull

typedef unsigned short u16;
typedef __attribute__((ext_vector_type(8))) short bf16x8;
typedef __attribute__((ext_vector_type(4))) float f32x4;
#define MFMA16(a, b, c) __builtin_amdgcn_mfma_f32_16x16x32_bf16(a, b, c, 0, 0, 0)

static __device__ __forceinline__ float sigm(float x) { return 1.0f / (1.0f + expf(-x)); }

static __device__ __forceinline__ float b2f(u16 u) {
    union { float f; unsigned int i; } v; v.i = ((unsigned int)u) << 16; return v.f;
}
static __device__ __forceinline__ u16 f2b(float f) {
    union { float f; unsigned int i; } v; v.f = f;
    unsigned int r = v.i + 0x7fffu + ((v.i >> 16) & 1u);
    return (u16)(r >> 16);
}
static __device__ __forceinline__ void b8ld(const u16* p, float* d) {
    uint4 u = *(const uint4*)p;
    d[0] = b2f((u16)(u.x & 0xffff)); d[1] = b2f((u16)(u.x >> 16));
    d[2] = b2f((u16)(u.y & 0xffff)); d[3] = b2f((u16)(u.y >> 16));
    d[4] = b2f((u16)(u.z & 0xffff)); d[5] = b2f((u16)(u.z >> 16));
    d[6] = b2f((u16)(u.w & 0xffff)); d[7] = b2f((u16)(u.w >> 16));
}
static __device__ __forceinline__ void b8st(const float* s, u16* p) {
    uint4 u;
    u.x = (unsigned)f2b(s[0]) | ((unsigned)f2b(s[1]) << 16);
    u.y = (unsigned)f2b(s[2]) | ((unsigned)f2b(s[3]) << 16);
    u.z = (unsigned)f2b(s[4]) | ((unsigned)f2b(s[5]) << 16);
    u.w = (unsigned)f2b(s[6]) | ((unsigned)f2b(s[7]) << 16);
    *(uint4*)p = u;
}
static __device__ __forceinline__ float4 ldA4(const u16* p) {
    ushort4 u = *(const ushort4*)p;
    float4 f; f.x = b2f(u.x); f.y = b2f(u.y); f.z = b2f(u.z); f.w = b2f(u.w); return f;
}
static __device__ __forceinline__ void cstore(float* p, float v) { *p = v; }
static __device__ __forceinline__ void cstore(u16* p, float v) { *p = f2b(v); }

// async 16B global -> LDS (dest = wave-uniform base + lane*16; our layout is
// lane-consecutive by construction)
static __device__ __forceinline__ void async16(const u16* g, u16* l) {
    __builtin_amdgcn_global_load_lds(
        (const __attribute__((address_space(1))) unsigned int*)g,
        (__attribute__((address_space(3))) unsigned int*)l, 16, 0, 0);
}

// fp32 -> bf16 bulk convert (n multiple of 8; one 8-elt group per thread)
__global__ __launch_bounds__(256) void cvt_f2b(const float* __restrict__ in,
                                               u16* __restrict__ out, int n8) {
    int i = blockIdx.x * 256 + threadIdx.x;
    if (i >= n8) return;
    float t[8];
    float4 a = *(const float4*)(in + (size_t)i * 8);
    float4 b = *(const float4*)(in + (size_t)i * 8 + 4);
    t[0] = a.x; t[1] = a.y; t[2] = a.z; t[3] = a.w;
    t[4] = b.x; t[5] = b.y; t[6] = b.z; t[7] = b.w;
    b8st(t, out + (size_t)i * 8);
}

// ---------------------------------------------------------------------------
// m97-style async MFMA GEMM: C[M,N] = A[M,K] @ B[N,K]^T, bf16 in, fp32 acc.
// 128x128 tile, BK=64, 4 waves (64x64 quadrant each, 4x4 16x16x32 tiles).
// LDS: unpadded 128x64 bf16 tiles, octets XOR-swizzled (slot c holds global
// octet (c&7)^(row&7)) so fragment ds_read_b128 is 2-way max (free).
// ---------------------------------------------------------------------------
template <typename TC>
__global__ __launch_bounds__(256) void gemm_bt_async(const u16* __restrict__ A,
                                                     const u16* __restrict__ Bm,
                                                     TC* __restrict__ Cm,
                                                     int M, int N, int K) {
    __shared__ __align__(16) u16 sA[128 * 64];
    __shared__ __align__(16) u16 sB[128 * 64];
    const int tid = threadIdx.x;
    const int w = tid >> 6, lane = tid & 63, lq = lane >> 4, ln = lane & 15;
    const int wm = w >> 1, wn = w & 1;
    const int mbase = blockIdx.y * 128, nbase = blockIdx.x * 128;

    f32x4 acc[4][4];
#pragma unroll
    for (int mt = 0; mt < 4; mt++)
#pragma unroll
        for (int nt = 0; nt < 4; nt++) acc[mt][nt] = (f32x4){0.f, 0.f, 0.f, 0.f};

    for (int k0 = 0; k0 < K; k0 += 64) {
#pragma unroll
        for (int j = 0; j < 4; j++) {
            int c = tid + 256 * j;                 // LDS chunk slot 0..1023
            int row = c >> 3;
            int oct = (c & 7) ^ (row & 7);         // swizzled source octet
            async16(A + (size_t)(mbase + row) * K + k0 + oct * 8, &sA[c * 8]);
            async16(Bm + (size_t)(nbase + row) * K + k0 + oct * 8, &sB[c * 8]);
        }
        __syncthreads();
#pragma unroll
        for (int ks = 0; ks < 2; ks++) {
            const int o = ks * 4 + lq;             // k-octet this quarter needs
            bf16x8 af[4], bfr[4];
#pragma unroll
            for (int mt = 0; mt < 4; mt++) {
                int m = wm * 64 + mt * 16 + ln;
                af[mt] = *(const bf16x8*)&sA[(m << 6) + ((o ^ (m & 7)) << 3)];
            }
#pragma unroll
            for (int nt = 0; nt < 4; nt++) {
                int nn = wn * 64 + nt * 16 + ln;
                bfr[nt] = *(const bf16x8*)&sB[(nn << 6) + ((o ^ (nn & 7)) << 3)];
            }
#pragma unroll
            for (int mt = 0; mt < 4; mt++)
#pragma unroll
                for (int nt = 0; nt < 4; nt++)
                    acc[mt][nt] = MFMA16(af[mt], bfr[nt], acc[mt][nt]);
        }
        __syncthreads();
    }
#pragma unroll
    for (int mt = 0; mt < 4; mt++)
#pragma unroll
        for (int nt = 0; nt < 4; nt++) {
            int col = nbase + wn * 64 + nt * 16 + ln;
#pragma unroll
            for (int r = 0; r < 4; r++) {
                int row = mbase + wm * 64 + mt * 16 + lq * 4 + r;
                cstore(Cm + (size_t)row * N + col, acc[mt][nt][r]);
            }
        }
}

// ---------------------------------------------------------------------------
// Causal depthwise conv (KW=4) + SiLU + optional L2 norm over Dh.
// ---------------------------------------------------------------------------
__global__ __launch_bounds__(256) void conv_silu_norm(const u16* __restrict__ pre,
                                                      const float* __restrict__ w,
                                                      u16* __restrict__ out, int mode) {
    int wid = blockIdx.x * 4 + (threadIdx.x >> 6);
    int lane = threadIdx.x & 63;
    int l = wid & (L_ - 1);
    int bh = wid >> 12;
    int b = bh >> 4, h = bh & 15;

    float vals[2];
    float sumsq = 0.0f;
#pragma unroll
    for (int s = 0; s < 2; s++) {
        int d = lane + 64 * s;
        int c = h * DH + d;
        const u16* col = pre + (size_t)b * L_ * HD + c;
        float acc = 0.0f;
        if (l >= 3) {
            acc = w[c * 4 + 0] * b2f(col[(size_t)(l - 3) * HD]) +
                  w[c * 4 + 1] * b2f(col[(size_t)(l - 2) * HD]) +
                  w[c * 4 + 2] * b2f(col[(size_t)(l - 1) * HD]) +
                  w[c * 4 + 3] * b2f(col[(size_t)l * HD]);
        } else {
#pragma unroll
            for (int j = 0; j < 4; j++) {
                int ll = l - 3 + j;
                if (ll >= 0) acc += w[c * 4 + j] * b2f(col[(size_t)ll * HD]);
            }
        }
        float y = acc * sigm(acc);
        vals[s] = y;
        sumsq += y * y;
    }
    if (mode < 2) {
#pragma unroll
        for (int m = 32; m >= 1; m >>= 1) sumsq += __shfl_xor(sumsq, m, 64);
        float scale = 1.0f / fmaxf(sqrtf(sumsq), 1e-12f);
        if (mode == 0) scale *= 0.08838834764831843f;
        vals[0] *= scale;
        vals[1] *= scale;
    }
    u16* o = out + ((size_t)bh * L_ + l) * DH;
    o[lane] = f2b(vals[0]);
    o[lane + 64] = f2b(vals[1]);
}

__global__ __launch_bounds__(64) void proj_small(const float* __restrict__ x,
                                                 const float* __restrict__ Wb,
                                                 const float* __restrict__ Wa,
                                                 float* __restrict__ bpre,
                                                 float* __restrict__ apre) {
    int row = blockIdx.x;
    int lane = threadIdx.x;
    const float* xr = x + (size_t)row * D_;
    float xv[32];
#pragma unroll
    for (int j = 0; j < 32; j++) xv[j] = xr[lane + 64 * j];
    for (int h = 0; h < 16; h++) {
        const float* wr = Wb + (size_t)h * D_;
        float acc = 0.0f;
#pragma unroll
        for (int j = 0; j < 32; j++) acc += xv[j] * wr[lane + 64 * j];
#pragma unroll
        for (int m = 32; m >= 1; m >>= 1) acc += __shfl_xor(acc, m, 64);
        if (lane == 0) bpre[(size_t)row * 16 + h] = acc;
    }
    for (int h = 0; h < 16; h++) {
        const float* wr = Wa + (size_t)h * D_;
        float acc = 0.0f;
#pragma unroll
        for (int j = 0; j < 32; j++) acc += xv[j] * wr[lane + 64 * j];
#pragma unroll
        for (int m = 32; m >= 1; m >>= 1) acc += __shfl_xor(acc, m, 64);
        if (lane == 0) apre[(size_t)row * 16 + h] = acc;
    }
}

__global__ __launch_bounds__(256) void beta_g_k(const float* __restrict__ bpre,
                                                const float* __restrict__ apre,
                                                const float* __restrict__ A_log,
                                                const float* __restrict__ dt_bias,
                                                float* __restrict__ beta, float* __restrict__ g) {
    int gi = blockIdx.x * 256 + threadIdx.x;
    int l = gi & (L_ - 1);
    int bh = gi >> 12;
    int b = bh >> 4, h = bh & 15;
    float bp = bpre[((size_t)b * L_ + l) * 16 + h];
    float ap = apre[((size_t)b * L_ + l) * 16 + h] + dt_bias[h];
    float sp = (ap > 20.0f) ? ap : log1pf(expf(ap));
    beta[(size_t)bh * L_ + l] = 1.0f / (1.0f + expf(-bp));
    g[(size_t)bh * L_ + l] = -expf(A_log[h]) * sp;
}

// ---------------------------------------------------------------------------
// Per-chunk prep (2048 blocks).
// ---------------------------------------------------------------------------
__global__ __launch_bounds__(256) void prep_chunks(u16* __restrict__ q, u16* __restrict__ k,
                                                   u16* __restrict__ v,
                                                   const float* __restrict__ beta,
                                                   const float* __restrict__ g,
                                                   u16* __restrict__ Wm, u16* __restrict__ W2,
                                                   float* __restrict__ gamC) {
    __shared__ __align__(16) float sK[CH * DH];
    __shared__ __align__(16) float sA[CH * CH];
    __shared__ float sLg[CH], sGam[CH], sGcr[CH], sBeta[CH];

    const int cid = blockIdx.x;
    const int bh = cid >> 6, n = cid & 63;
    const int tid = threadIdx.x;
    const size_t cbase = ((size_t)bh * L_ + (size_t)n * CH) * DH;
    u16* qw = q + cbase;
    u16* kw = k + cbase;
    const u16* vc = v + cbase;

    if (tid < 64) {
        float lg = g[(size_t)bh * L_ + (size_t)n * CH + tid];
#pragma unroll
        for (int off = 1; off < 64; off <<= 1) {
            float u = __shfl_up(lg, off, 64);
            if (tid >= off) lg += u;
        }
        float lgC = __shfl(lg, 63, 64);
        sLg[tid] = lg;
        sGam[tid] = expf(lg);
        sGcr[tid] = expf(lgC - lg);
        sBeta[tid] = beta[(size_t)bh * L_ + (size_t)n * CH + tid];
        if (tid == 63) gamC[cid] = expf(lgC);
    }
    for (int idx = tid; idx < CH * DH / 8; idx += 256)
        b8ld(kw + (size_t)idx * 8, &sK[idx * 8]);
    __syncthreads();

    {
        int bi = tid >> 4, bj = tid & 15;
        int i0 = bi * 4, j0 = bj * 4;
        u16* w2c = W2 + (size_t)cid * CH * CH;
        if (bi >= bj) {
            float dotA[4][4], dotQ[4][4];
#pragma unroll
            for (int r = 0; r < 4; r++)
#pragma unroll
                for (int c = 0; c < 4; c++) { dotA[r][c] = 0.0f; dotQ[r][c] = 0.0f; }
            for (int e = 0; e < DH; e += 4) {
                float4 ka[4], kb[4], qa[4];
#pragma unroll
                for (int r = 0; r < 4; r++) {
                    ka[r] = *(const float4*)&sK[(i0 + r) * DH + e];
                    qa[r] = ldA4(qw + (size_t)(i0 + r) * DH + e);
                }
#pragma unroll
                for (int c = 0; c < 4; c++) kb[c] = *(const float4*)&sK[(j0 + c) * DH + e];
#pragma unroll
                for (int r = 0; r < 4; r++)
#pragma unroll
                    for (int c = 0; c < 4; c++) {
                        dotA[r][c] += ka[r].x * kb[c].x + ka[r].y * kb[c].y + ka[r].z * kb[c].z + ka[r].w * kb[c].w;
                        dotQ[r][c] += qa[r].x * kb[c].x + qa[r].y * kb[c].y + qa[r].z * kb[c].z + qa[r].w * kb[c].w;
                    }
            }
#pragma unroll
            for (int r = 0; r < 4; r++)
#pragma unroll
                for (int c = 0; c < 4; c++) {
                    int i = i0 + r, j = j0 + c;
                    float dexp = expf(sLg[i] - sLg[j]);
                    sA[i * CH + j] = (j < i) ? sBeta[i] * dexp * dotA[r][c] : ((j == i) ? 1.0f : 0.0f);
                    w2c[i * CH + j] = f2b((j <= i) ? dotQ[r][c] * dexp : 0.0f);
                }
        } else {
#pragma unroll
            for (int r = 0; r < 4; r++)
#pragma unroll
                for (int c = 0; c < 4; c++) {
                    sA[(i0 + r) * CH + j0 + c] = 0.0f;
                    w2c[(i0 + r) * CH + j0 + c] = 0;
                }
        }
    }
    __syncthreads();

    for (int idx = tid; idx < CH * DH; idx += 256) {
        int i = idx >> 7;
        qw[idx] = f2b(b2f(qw[idx]) * sGam[i]);
        kw[idx] = f2b(b2f(kw[idx]) * sGcr[i]);
        sK[idx] *= sBeta[i] * sGam[i];
    }
    __syncthreads();

    for (int i = 1; i < 64; i++) {
        float xj = 0.0f;
        bool act = (tid < i);
        if (act) {
            float acc2 = 0.0f;
            for (int kk = 0; kk < i; kk++) acc2 += sA[i * CH + kk] * sA[kk * CH + tid];
            xj = -acc2;
        }
        __syncthreads();
        if (act) sA[i * CH + tid] = xj;
        __syncthreads();
    }

    {
        int ib = tid >> 4, cb = tid & 15;
        int i0 = ib * 4, c0 = cb * 8;
        float accK[4][8], accV[4][8];
#pragma unroll
        for (int r = 0; r < 4; r++)
#pragma unroll
            for (int c = 0; c < 8; c++) { accK[r][c] = 0.0f; accV[r][c] = 0.0f; }
        for (int kk = 0; kk < CH; kk += 4) {
            float tr[4][4];
#pragma unroll
            for (int r = 0; r < 4; r++) {
                float4 t4 = *(const float4*)&sA[(i0 + r) * CH + kk];
                tr[r][0] = t4.x; tr[r][1] = t4.y; tr[r][2] = t4.z; tr[r][3] = t4.w;
            }
#pragma unroll
            for (int s = 0; s < 4; s++) {
                int kks = kk + s;
                float va[8], ka[8];
                b8ld(vc + (size_t)kks * DH + c0, va);
                float bv = sBeta[kks];
#pragma unroll
                for (int c = 0; c < 8; c++) { va[c] *= bv; ka[c] = sK[kks * DH + c0 + c]; }
#pragma unroll
                for (int r = 0; r < 4; r++) {
                    float t = tr[r][s];
#pragma unroll
                    for (int c = 0; c < 8; c++) {
                        accK[r][c] += t * ka[c];
                        accV[r][c] += t * va[c];
                    }
                }
            }
        }
        u16* wmc = Wm + (size_t)cid * CH * DH;
#pragma unroll
        for (int r = 0; r < 4; r++) b8st(&accK[r][0], wmc + (size_t)(i0 + r) * DH + c0);
        __syncthreads();
        u16* uc = v + cbase;
#pragma unroll
        for (int r = 0; r < 4; r++) b8st(&accV[r][0], uc + (size_t)(i0 + r) * DH + c0);
    }
}

// ---------------------------------------------------------------------------
// MFMA inter-chunk scan (256 blocks = BH * 8 d-groups of 16).
// ---------------------------------------------------------------------------
__global__ __launch_bounds__(256) void scan_mfma(const u16* __restrict__ Wm,
                                                 const u16* __restrict__ U,
                                                 const u16* __restrict__ Qd,
                                                 const u16* __restrict__ Kd,
                                                 const u16* __restrict__ W2,
                                                 const float* __restrict__ gamC,
                                                 const float* __restrict__ S0,
                                                 float* __restrict__ Og,
                                                 float* __restrict__ Sfin) {
    __shared__ __align__(16) u16 sWm[64 * 136];
    __shared__ __align__(16) u16 sQd[64 * 136];
    __shared__ __align__(16) u16 sKdT[128 * 72];
    __shared__ __align__(16) u16 sW2[64 * 72];
    __shared__ __align__(16) u16 sS[16 * 136];
    __shared__ __align__(16) u16 sMidT[16 * 72];

    const int bid = blockIdx.x;
    const int bh = bid >> 3, dg = bid & 7, d0 = dg * 16;
    const int tid = threadIdx.x;
    const int w = tid >> 6, lane = tid & 63, lq = lane >> 4, ln = lane & 15;

    f32x4 S_t[2];
#pragma unroll
    for (int t2 = 0; t2 < 2; t2++)
#pragma unroll
        for (int r = 0; r < 4; r++)
            S_t[t2][r] = S0[(size_t)bh * DH * DH + (size_t)(d0 + lq * 4 + r) * DH + w * 32 + t2 * 16 + ln];

    for (int n = 0; n < NCH; n++) {
        const size_t cid = (size_t)bh * NCH + n;
        const u16* wmc = Wm + cid * CH * DH;
        const size_t tb = ((size_t)bh * L_ + (size_t)n * CH) * DH;
        const u16* uc = U + tb;
        const u16* qc = Qd + tb;
        const u16* kc = Kd + tb;
        const u16* w2c = W2 + cid * CH * CH;
        const float gC = gamC[cid];

#pragma unroll
        for (int t2 = 0; t2 < 2; t2++)
#pragma unroll
            for (int r = 0; r < 4; r++)
                sS[(lq * 4 + r) * 136 + w * 32 + t2 * 16 + ln] = f2b(S_t[t2][r]);

#pragma unroll
        for (int j = 0; j < 4; j++) {
            int f = tid + 256 * j;
            int row = f >> 4, kc8 = (f & 15) * 8;
            *(uint4*)&sWm[row * 136 + kc8] = *(const uint4*)(wmc + f * 8);
            *(uint4*)&sQd[row * 136 + kc8] = *(const uint4*)(qc + f * 8);
        }
#pragma unroll
        for (int j = 0; j < 2; j++) {
            int f = tid + 256 * j;
            int row = f >> 3, c8 = (f & 7) * 8;
            *(uint4*)&sW2[row * 72 + c8] = *(const uint4*)(w2c + f * 8);
        }
#pragma unroll
        for (int rep = 0; rep < 8; rep++) {
            int f = tid + 256 * rep;
            int i = f >> 5, e4 = (f & 31) * 4;
            ushort4 vv = *(const ushort4*)(kc + (size_t)f * 4);
            sKdT[(e4 + 0) * 72 + i] = vv.x;
            sKdT[(e4 + 1) * 72 + i] = vv.y;
            sKdT[(e4 + 2) * 72 + i] = vv.z;
            sKdT[(e4 + 3) * 72 + i] = vv.w;
        }
        __syncthreads();

        // G1: mid = U - Wm @ S^T
        f32x4 macc = (f32x4){0.f, 0.f, 0.f, 0.f};
#pragma unroll
        for (int ks = 0; ks < 4; ks++) {
            bf16x8 a = *(const bf16x8*)&sWm[(w * 16 + ln) * 136 + ks * 32 + lq * 8];
            bf16x8 b = *(const bf16x8*)&sS[ln * 136 + ks * 32 + lq * 8];
            macc = MFMA16(a, b, macc);
        }
#pragma unroll
        for (int r = 0; r < 4; r++) {
            int i = w * 16 + lq * 4 + r;
            float mv = b2f(uc[(size_t)i * DH + d0 + ln]) - macc[r];
            sMidT[ln * 72 + i] = f2b(mv);
        }
        __syncthreads();

        // G2: O = Qd @ S^T + W2 @ mid
        f32x4 oacc = (f32x4){0.f, 0.f, 0.f, 0.f};
#pragma unroll
        for (int ks = 0; ks < 4; ks++) {
            bf16x8 a = *(const bf16x8*)&sQd[(w * 16 + ln) * 136 + ks * 32 + lq * 8];
            bf16x8 b = *(const bf16x8*)&sS[ln * 136 + ks * 32 + lq * 8];
            oacc = MFMA16(a, b, oacc);
        }
#pragma unroll
        for (int ks = 0; ks < 2; ks++) {
            bf16x8 a = *(const bf16x8*)&sW2[(w * 16 + ln) * 72 + ks * 32 + lq * 8];
            bf16x8 b = *(const bf16x8*)&sMidT[ln * 72 + ks * 32 + lq * 8];
            oacc = MFMA16(a, b, oacc);
        }
#pragma unroll
        for (int r = 0; r < 4; r++) {
            int i = w * 16 + lq * 4 + r;
            Og[((size_t)bh * L_ + (size_t)n * CH + i) * DH + d0 + ln] = oacc[r];
        }

        // G3: S = gC*S + mid^T @ Kd
#pragma unroll
        for (int t2 = 0; t2 < 2; t2++)
#pragma unroll
            for (int r = 0; r < 4; r++) S_t[t2][r] *= gC;
#pragma unroll
        for (int ks = 0; ks < 2; ks++) {
            bf16x8 a = *(const bf16x8*)&sMidT[ln * 72 + ks * 32 + lq * 8];
#pragma unroll
            for (int t2 = 0; t2 < 2; t2++) {
                bf16x8 b = *(const bf16x8*)&sKdT[((2 * w + t2) * 16 + ln) * 72 + ks * 32 + lq * 8];
                S_t[t2] = MFMA16(a, b, S_t[t2]);
            }
        }
        __syncthreads();
    }

#pragma unroll
    for (int t2 = 0; t2 < 2; t2++)
#pragma unroll
        for (int r = 0; r < 4; r++)
            Sfin[(size_t)bh * DH * DH + (size_t)(d0 + lq * 4 + r) * DH + w * 32 + t2 * 16 + ln] = S_t[t2][r];
}

__global__ __launch_bounds__(256) void epilogue_gate(const float* __restrict__ Ob,
                                                     const u16* __restrict__ gpre,
                                                     const float* __restrict__ norm_w,
                                                     u16* __restrict__ gated) {
    int wid = blockIdx.x * 4 + (threadIdx.x >> 6);
    int lane = threadIdx.x & 63;
    int l = wid & (L_ - 1);
    int bh = wid >> 12;
    int b = bh >> 4, h = bh & 15;
    const float* orow = Ob + ((size_t)bh * L_ + l) * DH;
    float o0 = orow[lane], o1 = orow[lane + 64];
    float ss = o0 * o0 + o1 * o1;
#pragma unroll
    for (int m = 32; m >= 1; m >>= 1) ss += __shfl_xor(ss, m, 64);
    float r = rsqrtf(ss * (1.0f / 128.0f) + 1e-5f);
    size_t gidx = ((size_t)b * L_ + l) * HD + h * DH;
    float gp0 = b2f(gpre[gidx + lane]), gp1 = b2f(gpre[gidx + lane + 64]);
    gated[gidx + lane] = f2b(o0 * r * norm_w[lane] * (gp0 * sigm(gp0)));
    gated[gidx + lane + 64] = f2b(o1 * r * norm_w[lane + 64] * (gp1 * sigm(gp1)));
}

// ---------------------------------------------------------------------------
extern "C" void kernel_launch(void* const* d_in, const int* in_sizes, int n_in,
                              void* d_out, int out_size, void* d_ws, size_t ws_size,
                              hipStream_t stream) {
    const float* x       = (const float*)d_in[0];
    const float* Wq      = (const float*)d_in[1];
    const float* Wk      = (const float*)d_in[2];
    const float* Wv      = (const float*)d_in[3];
    const float* Wb      = (const float*)d_in[4];
    const float* Wa      = (const float*)d_in[5];
    const float* A_log   = (const float*)d_in[6];
    const float* dt_bias = (const float*)d_in[7];
    const float* conv_q  = (const float*)d_in[8];
    const float* conv_k  = (const float*)d_in[9];
    const float* conv_v  = (const float*)d_in[10];
    const float* Wg      = (const float*)d_in[11];
    const float* norm_w  = (const float*)d_in[12];
    const float* Wo      = (const float*)d_in[13];
    const float* S0      = (const float*)d_in[14];
    float* out = (float*)d_out;

    // Workspace (~195 MB, u16 units):
    //   Pb (preact scratch -> Wm), Qb (q->Qd), Kb (k->Kd -> gated),
    //   Vb (v->U -> gpre), W2b, xb (bf16 x), wbuf (rotating bf16 weight).
    // O (fp32) lives in d_out[0:PSZ]; Sfin in d_out[PSZ:].
    u16* Pb = (u16*)d_ws;
    u16* Qb = Pb + PSZ;
    u16* Kb = Qb + PSZ;
    u16* Vb = Kb + PSZ;
    u16* W2b = Vb + PSZ;                        // PSZ/2 u16
    u16* xb  = W2b + PSZ / 2;                   // PSZ u16
    u16* wbuf = xb + PSZ;                       // 2048*2048 u16
    float* bpre = (float*)(wbuf + 4194304);
    float* apre = bpre + BHL;
    float* betab = apre + BHL;
    float* gbuf = betab + BHL;
    float* gamC = gbuf + BHL;                   // 2048

    float* Obuf = out;
    float* Sfin = out + PSZ;

    dim3 gblk(16, 64);  // (N/128, M/128) for M=8192,N=2048
    const int W8 = 2048 * 2048 / 8;             // weight cvt groups

    cvt_f2b<<<8192, 256, 0, stream>>>(x, xb, (int)(PSZ / 8));
    cvt_f2b<<<2048, 256, 0, stream>>>(Wq, wbuf, W8);
    gemm_bt_async<u16><<<gblk, 256, 0, stream>>>(xb, wbuf, Pb, 8192, 2048, 2048);
    conv_silu_norm<<<32768, 256, 0, stream>>>(Pb, conv_q, Qb, 0);
    cvt_f2b<<<2048, 256, 0, stream>>>(Wk, wbuf, W8);
    gemm_bt_async<u16><<<gblk, 256, 0, stream>>>(xb, wbuf, Pb, 8192, 2048, 2048);
    conv_silu_norm<<<32768, 256, 0, stream>>>(Pb, conv_k, Kb, 1);
    cvt_f2b<<<2048, 256, 0, stream>>>(Wv, wbuf, W8);
    gemm_bt_async<u16><<<gblk, 256, 0, stream>>>(xb, wbuf, Pb, 8192, 2048, 2048);
    conv_silu_norm<<<32768, 256, 0, stream>>>(Pb, conv_v, Vb, 2);
    proj_small<<<8192, 64, 0, stream>>>(x, Wb, Wa, bpre, apre);
    beta_g_k<<<512, 256, 0, stream>>>(bpre, apre, A_log, dt_bias, betab, gbuf);
    prep_chunks<<<2048, 256, 0, stream>>>(Qb, Kb, Vb, betab, gbuf, Pb, W2b, gamC);
    scan_mfma<<<256, 256, 0, stream>>>(Pb, Vb, Qb, Kb, W2b, gamC, S0, Obuf, Sfin);
    // g projection after the scan: gpre reuses Vb (U is dead now)
    cvt_f2b<<<2048, 256, 0, stream>>>(Wg, wbuf, W8);
    gemm_bt_async<u16><<<gblk, 256, 0, stream>>>(xb, wbuf, Vb, 8192, 2048, 2048);
    epilogue_gate<<<32768, 256, 0, stream>>>(Obuf, Vb, norm_w, Kb);
    cvt_f2b<<<2048, 256, 0, stream>>>(Wo, wbuf, W8);
    gemm_bt_async<float><<<gblk, 256, 0, stream>>>(Kb, wbuf, out, 8192, 2048, 2048);
}